// Round 4
// baseline (451.039 us; speedup 1.0000x reference)
//
#include <hip/hip_runtime.h>
#include <hip/hip_bf16.h>
#include <hip/hip_cooperative_groups.h>

namespace cg = cooperative_groups;

#define D_MODEL 1024
#define NUM_HEADS 16
#define HEAD_DIM 64
#define BATCH 2
#define SEQ 2048
#define M_TOT (BATCH*SEQ)      // 4096
#define CHUNK 64
#define NCHUNK (SEQ/CHUNK)     // 32
#define LT 68                  // LDS stride (ushorts) for attention tiles

typedef __attribute__((ext_vector_type(8))) short bf16x8;
typedef __attribute__((ext_vector_type(8))) unsigned short us16x8;
typedef __attribute__((ext_vector_type(4))) float f32x4;

__device__ inline ushort f2bf(float f) {
    __hip_bfloat16 h = __float2bfloat16(f);
    return __builtin_bit_cast(ushort, h);
}
__device__ inline float bf2f(ushort u) {
    unsigned int v = ((unsigned int)u) << 16;
    return __builtin_bit_cast(float, v);
}

__device__ inline bf16x8 ld_frag(const ushort* p) {
    struct S { uint2 a, b; };
    S s;
    s.a = *(const uint2*)p;
    s.b = *(const uint2*)(p + 4);
    return __builtin_bit_cast(bf16x8, s);
}

__device__ inline void st16(ushort* dst, uint4 a, uint4 b) {
    *(uint2*)(dst + 0)  = make_uint2(a.x, a.y);
    *(uint2*)(dst + 4)  = make_uint2(a.z, a.w);
    *(uint2*)(dst + 8)  = make_uint2(b.x, b.y);
    *(uint2*)(dst + 12) = make_uint2(b.z, b.w);
}

// async global->LDS, 16B per lane; LDS dst is wave-uniform base + lane*16
__device__ inline void load_lds16(const ushort* g, ushort* l) {
    __builtin_amdgcn_global_load_lds(
        (const __attribute__((address_space(1))) unsigned int*)g,
        (__attribute__((address_space(3))) unsigned int*)l, 16, 0, 0);
}

// ---------------- fused cast fp32 -> bf16 (x|Wq|Wk|Wv|Wo) + decay table ----------------
#define XN (M_TOT * D_MODEL)              // 4194304
#define WN (D_MODEL * D_MODEL)            // 1048576
#define CAST_BLOCKS ((XN + 4 * WN) / 4 / 256)   // 8192
__global__ __launch_bounds__(256) void cast_all_kernel(const float* __restrict__ x,
                                                       const float* __restrict__ Wq,
                                                       const float* __restrict__ Wk,
                                                       const float* __restrict__ Wv,
                                                       const float* __restrict__ Wo,
                                                       ushort* __restrict__ dst,
                                                       const float* __restrict__ gamma,
                                                       float* __restrict__ decay) {
    int bx = blockIdx.x;
    if (bx >= CAST_BLOCKS) {  // decay region: gamma[h]^i
        int idx = (bx - CAST_BLOCKS) * 256 + threadIdx.x;   // 32768 total
        int i = idx >> 4, h = idx & 15;
        decay[idx] = powf(gamma[h], (float)i);
        return;
    }
    size_t o = ((size_t)bx * 256 + threadIdx.x) * 4;
    const float* src;
    if (o < XN)               src = x  + o;
    else if (o < XN + WN)     src = Wq + (o - XN);
    else if (o < XN + 2 * WN) src = Wk + (o - XN - WN);
    else if (o < XN + 3 * WN) src = Wv + (o - XN - 2 * (size_t)WN);
    else                      src = Wo + (o - XN - 3 * (size_t)WN);
    float4 f = *(const float4*)src;
    ushort4 u;
    u.x = f2bf(f.x); u.y = f2bf(f.y); u.z = f2bf(f.z); u.w = f2bf(f.w);
    *(ushort4*)(dst + o) = u;
}

// ---------------- 128x128-tile MFMA GEMM, global_load_lds staging, XOR-swizzled LDS ----
template <int NBUF, int OUT_BF16>
__global__ __launch_bounds__(256) void gemm128(const ushort* __restrict__ A,
                                               const ushort* __restrict__ Bt,
                                               const float* __restrict__ b0,
                                               const float* __restrict__ b1,
                                               const float* __restrict__ b2,
                                               void* __restrict__ o0,
                                               void* __restrict__ o1,
                                               void* __restrict__ o2,
                                               const float* __restrict__ decay) {
    const int K = 1024;
    __shared__ ushort lds_a[128 * 64];   // 16 KB, row-major, chunk-col XOR-swizzled
    __shared__ ushort lds_b[128 * 64];
    int t = threadIdx.x;
    int lane = t & 63, w = t >> 6;
    int bm = blockIdx.y * 128, bn = blockIdx.x * 128;
    int wm = (w >> 1) * 64, wn = (w & 1) * 64;

    int lr = lane >> 3, lc = lane & 7;
    int gcol = lc ^ (lr & 7);
    const ushort* aBase = A  + (size_t)(bm + w * 32 + lr) * K + gcol * 8;
    const ushort* bBase = Bt + (size_t)(bn + w * 32 + lr) * K + gcol * 8;
    ushort* aLds = &lds_a[(w * 32) * 64];
    ushort* bLds = &lds_b[(w * 32) * 64];

    f32x4 acc[4][4];
    #pragma unroll
    for (int i = 0; i < 4; i++)
        #pragma unroll
        for (int j = 0; j < 4; j++)
            acc[i][j] = (f32x4){0.f, 0.f, 0.f, 0.f};

    int mrel = lane & 15, kq = lane >> 4;

    for (int k0 = 0; k0 < K; k0 += 64) {
        #pragma unroll
        for (int q = 0; q < 4; q++) {
            load_lds16(aBase + (size_t)q * 8 * K + k0, aLds + q * 512);
            load_lds16(bBase + (size_t)q * 8 * K + k0, bLds + q * 512);
        }
        __syncthreads();
        #pragma unroll
        for (int s = 0; s < 2; s++) {
            bf16x8 af[4], bfv[4];
            #pragma unroll
            for (int i = 0; i < 4; i++) {
                int row = wm + i * 16 + mrel;
                af[i] = ld_frag(&lds_a[row * 64 + (((s * 4 + kq) ^ (row & 7)) * 8)]);
            }
            #pragma unroll
            for (int j = 0; j < 4; j++) {
                int row = wn + j * 16 + mrel;
                bfv[j] = ld_frag(&lds_b[row * 64 + (((s * 4 + kq) ^ (row & 7)) * 8)]);
            }
            #pragma unroll
            for (int i = 0; i < 4; i++)
                #pragma unroll
                for (int j = 0; j < 4; j++)
                    acc[i][j] = __builtin_amdgcn_mfma_f32_16x16x32_bf16(af[i], bfv[j], acc[i][j], 0, 0, 0);
        }
        __syncthreads();
    }

    int quad = lane >> 4;
    int buf = (NBUF == 3) ? (bn >> 10) : 0;
    const float* bias = (buf == 0) ? b0 : (buf == 1) ? b1 : b2;
    void* dstv = (buf == 0) ? o0 : (buf == 1) ? o1 : o2;
    int cbase = ((NBUF == 3) ? (bn & 1023) : bn) + wn;
    #pragma unroll
    for (int j = 0; j < 4; j++) {
        int cl = cbase + j * 16 + mrel;
        float bv = bias[cl];
        #pragma unroll
        for (int i = 0; i < 4; i++) {
            #pragma unroll
            for (int reg = 0; reg < 4; reg++) {
                int row = bm + wm + i * 16 + quad * 4 + reg;
                float v = acc[i][j][reg] + bv;
                if (NBUF == 3 && buf == 0)
                    v *= decay[(row & (SEQ - 1)) * 16 + (cl >> 6)];
                if (OUT_BF16)
                    ((ushort*)dstv)[(size_t)row * 1024 + cl] = f2bf(v);
                else
                    ((float*)dstv)[(size_t)row * 1024 + cl] = v;
            }
        }
    }
}

// ======================= FUSED attention (cooperative, 1024 blocks) ====================
// Phase 1: per-chunk KV state (bf16) -> global. Phase 2: exclusive prefix scan in-place.
// Phase 3: O = Q'·S^T + causal(Q'K^T)·V, with K/V tiles kept in LDS across grid.sync().
// LDS: B1 = Kt -> Qs/Ps, B2 = Vt (persists), B3 = Ks natural (persists), B4 = acc/St.
__global__ __launch_bounds__(256, 4) void fused_attn(const ushort* __restrict__ qp,
                                                     const ushort* __restrict__ kp,
                                                     const ushort* __restrict__ vp,
                                                     ushort* __restrict__ statesb,
                                                     ushort* __restrict__ attn_out) {
    __shared__ ushort B1[64 * LT];
    __shared__ ushort B2[64 * LT];
    __shared__ ushort B3[64 * LT];
    __shared__ ushort B4[64 * LT];
    cg::grid_group grid = cg::this_grid();

    int bx = blockIdx.x;
    int c = bx & 31, h = (bx >> 5) & 15, b = bx >> 9;
    int t = threadIdx.x, lane = t & 63, w = t >> 6;
    size_t rowbase = (size_t)(b * SEQ + c * 64);
    int r = t >> 2, cc = t & 3;
    int mrel = lane & 15, q8 = (lane >> 4) * 8, quad = lane >> 4, band = w * 16;

    // ---- phase 1: stage K (natural + transposed), V (transposed) ----
    {
        const uint4* gk = (const uint4*)(kp + (rowbase + r) * D_MODEL + h * 64 + cc * 16);
        const uint4* gv = (const uint4*)(vp + (rowbase + r) * D_MODEL + h * 64 + cc * 16);
        uint4 k0 = gk[0], k1 = gk[1], v0 = gv[0], v1 = gv[1];
        st16(&B3[r * LT + cc * 16], k0, k1);   // K natural
        us16x8 ka = __builtin_bit_cast(us16x8, k0), kb = __builtin_bit_cast(us16x8, k1);
        us16x8 va = __builtin_bit_cast(us16x8, v0), vb = __builtin_bit_cast(us16x8, v1);
        #pragma unroll
        for (int i = 0; i < 8; i++) {
            B1[(cc * 16 + i) * LT + r]     = ka[i];   // K transposed
            B1[(cc * 16 + 8 + i) * LT + r] = kb[i];
            B2[(cc * 16 + i) * LT + r]     = va[i];   // V transposed
            B2[(cc * 16 + 8 + i) * LT + r] = vb[i];
        }
    }
    __syncthreads();
    // St[dv][dk] = sum_j V[j][dv] * K[j][dk]
    {
        bf16x8 af0 = ld_frag(&B2[(band + mrel) * LT + q8]);
        bf16x8 af1 = ld_frag(&B2[(band + mrel) * LT + 32 + q8]);
        f32x4 acc[4];
        #pragma unroll
        for (int dt = 0; dt < 4; dt++) acc[dt] = (f32x4){0.f, 0.f, 0.f, 0.f};
        #pragma unroll
        for (int dt = 0; dt < 4; dt++) {
            acc[dt] = __builtin_amdgcn_mfma_f32_16x16x32_bf16(
                af0, ld_frag(&B1[(dt * 16 + mrel) * LT + q8]), acc[dt], 0, 0, 0);
            acc[dt] = __builtin_amdgcn_mfma_f32_16x16x32_bf16(
                af1, ld_frag(&B1[(dt * 16 + mrel) * LT + 32 + q8]), acc[dt], 0, 0, 0);
        }
        // bf16 via LDS (B4) for coalesced global store
        #pragma unroll
        for (int dt = 0; dt < 4; dt++)
            #pragma unroll
            for (int reg = 0; reg < 4; reg++)
                B4[(band + quad * 4 + reg) * LT + dt * 16 + mrel] = f2bf(acc[dt][reg]);
    }
    __syncthreads();
    {
        bf16x8 s0 = ld_frag(&B4[r * LT + cc * 16]);
        bf16x8 s1 = ld_frag(&B4[r * LT + cc * 16 + 8]);
        uint4* dst = (uint4*)(statesb + (size_t)bx * 4096 + r * 64 + cc * 16);
        dst[0] = __builtin_bit_cast(uint4, s0);
        dst[1] = __builtin_bit_cast(uint4, s1);
    }
    grid.sync();

    // ---- phase 2: exclusive prefix over chunks, in place (512 active blocks) ----
    if (c < 16) {
        ushort* p = statesb + (size_t)(bx >> 5) * NCHUNK * 4096 + c * 256 + t;
        float run = 0.f;
        for (int cb = 0; cb < NCHUNK; cb += 8) {
            float vals[8];
            #pragma unroll
            for (int u = 0; u < 8; u++) vals[u] = bf2f(p[(size_t)(cb + u) * 4096]);
            #pragma unroll
            for (int u = 0; u < 8; u++) {
                p[(size_t)(cb + u) * 4096] = f2bf(run);
                run += vals[u];
            }
        }
    }
    grid.sync();

    // ---- phase 3: stage Q' -> B1, S_pre -> B4; K (B3) and Vt (B2) persist ----
    {
        const uint4* gq = (const uint4*)(qp + (rowbase + r) * D_MODEL + h * 64 + cc * 16);
        const uint4* gs = (const uint4*)(statesb + (size_t)bx * 4096 + t * 16);
        uint4 q0 = gq[0], q1 = gq[1];
        uint4 s0 = gs[0], s1 = gs[1];
        st16(&B1[r * LT + cc * 16], q0, q1);
        st16(&B4[(t >> 2) * LT + (t & 3) * 16], s0, s1);
    }
    __syncthreads();

    bf16x8 af0 = ld_frag(&B1[(band + mrel) * LT + q8]);
    bf16x8 af1 = ld_frag(&B1[(band + mrel) * LT + 32 + q8]);

    // inter-chunk: O[i][dv] = sum_dk Q'[i][dk] * Spre[dv][dk]
    f32x4 oacc[4];
    #pragma unroll
    for (int dt = 0; dt < 4; dt++) oacc[dt] = (f32x4){0.f, 0.f, 0.f, 0.f};
    #pragma unroll
    for (int dt = 0; dt < 4; dt++) {
        oacc[dt] = __builtin_amdgcn_mfma_f32_16x16x32_bf16(
            af0, ld_frag(&B4[(dt * 16 + mrel) * LT + q8]), oacc[dt], 0, 0, 0);
        oacc[dt] = __builtin_amdgcn_mfma_f32_16x16x32_bf16(
            af1, ld_frag(&B4[(dt * 16 + mrel) * LT + 32 + q8]), oacc[dt], 0, 0, 0);
    }

    // P = causal(Q'K^T); only j-tiles <= wave band nonzero
    f32x4 pacc[4];
    #pragma unroll
    for (int jt = 0; jt < 4; jt++) pacc[jt] = (f32x4){0.f, 0.f, 0.f, 0.f};
    #pragma unroll
    for (int jt = 0; jt < 4; jt++) {
        if (jt <= w) {
            pacc[jt] = __builtin_amdgcn_mfma_f32_16x16x32_bf16(
                af0, ld_frag(&B3[(jt * 16 + mrel) * LT + q8]), pacc[jt], 0, 0, 0);
            pacc[jt] = __builtin_amdgcn_mfma_f32_16x16x32_bf16(
                af1, ld_frag(&B3[(jt * 16 + mrel) * LT + 32 + q8]), pacc[jt], 0, 0, 0);
        }
    }
    // write P into B1's own wave band rows (Q frags already consumed into registers;
    // no other wave touches rows [band, band+16) -> no __syncthreads needed)
    #pragma unroll
    for (int jt = 0; jt < 4; jt++) {
        #pragma unroll
        for (int reg = 0; reg < 4; reg++) {
            int i = band + quad * 4 + reg;
            int j = jt * 16 + mrel;
            float val = (jt <= w && j <= i) ? pacc[jt][reg] : 0.f;
            B1[i * LT + j] = f2bf(val);
        }
    }

    // intra: O[i][dv] += sum_j P[i][j] * Vt[dv][j]
    bf16x8 pf0 = ld_frag(&B1[(band + mrel) * LT + q8]);
    #pragma unroll
    for (int dt = 0; dt < 4; dt++)
        oacc[dt] = __builtin_amdgcn_mfma_f32_16x16x32_bf16(
            pf0, ld_frag(&B2[(dt * 16 + mrel) * LT + q8]), oacc[dt], 0, 0, 0);
    if (w >= 2) {
        bf16x8 pf1 = ld_frag(&B1[(band + mrel) * LT + 32 + q8]);
        #pragma unroll
        for (int dt = 0; dt < 4; dt++)
            oacc[dt] = __builtin_amdgcn_mfma_f32_16x16x32_bf16(
                pf1, ld_frag(&B2[(dt * 16 + mrel) * LT + 32 + q8]), oacc[dt], 0, 0, 0);
    }

    #pragma unroll
    for (int dt = 0; dt < 4; dt++) {
        #pragma unroll
        for (int reg = 0; reg < 4; reg++) {
            size_t row = rowbase + band + quad * 4 + reg;
            int col = h * 64 + dt * 16 + mrel;
            attn_out[row * D_MODEL + col] = f2bf(oacc[dt][reg]);
        }
    }
}

// ======================= fallback (non-cooperative) path kernels =======================
__global__ __launch_bounds__(256) void chunk_kv_mfma(const ushort* __restrict__ kp,
                                                     const ushort* __restrict__ vp,
                                                     float* __restrict__ states) {
    __shared__ ushort Kt[64 * LT];
    __shared__ ushort Vt[64 * LT];
    int bx = blockIdx.x;
    int c = bx & 31, h = (bx >> 5) & 15, b = bx >> 9;
    int t = threadIdx.x, lane = t & 63, w = t >> 6;
    size_t rowbase = (size_t)(b * SEQ + c * 64);
    int r = t >> 2, cc = t & 3;
    const uint4* gk = (const uint4*)(kp + (rowbase + r) * D_MODEL + h * 64 + cc * 16);
    const uint4* gv = (const uint4*)(vp + (rowbase + r) * D_MODEL + h * 64 + cc * 16);
    uint4 k0 = gk[0], k1 = gk[1], v0 = gv[0], v1 = gv[1];
    {
        us16x8 ka = __builtin_bit_cast(us16x8, k0), kb = __builtin_bit_cast(us16x8, k1);
        us16x8 va = __builtin_bit_cast(us16x8, v0), vb = __builtin_bit_cast(us16x8, v1);
        #pragma unroll
        for (int i = 0; i < 8; i++) {
            Kt[(cc * 16 + i) * LT + r]     = ka[i];
            Kt[(cc * 16 + 8 + i) * LT + r] = kb[i];
            Vt[(cc * 16 + i) * LT + r]     = va[i];
            Vt[(cc * 16 + 8 + i) * LT + r] = vb[i];
        }
    }
    __syncthreads();
    int mrel = lane & 15, q8 = (lane >> 4) * 8, band = w * 16;
    bf16x8 af[2];
    af[0] = ld_frag(&Vt[(band + mrel) * LT + q8]);
    af[1] = ld_frag(&Vt[(band + mrel) * LT + 32 + q8]);
    f32x4 acc[4];
    #pragma unroll
    for (int dt = 0; dt < 4; dt++) acc[dt] = (f32x4){0.f, 0.f, 0.f, 0.f};
    #pragma unroll
    for (int dt = 0; dt < 4; dt++)
        #pragma unroll
        for (int kk = 0; kk < 2; kk++)
            acc[dt] = __builtin_amdgcn_mfma_f32_16x16x32_bf16(
                af[kk], ld_frag(&Kt[(dt * 16 + mrel) * LT + kk * 32 + q8]), acc[dt], 0, 0, 0);
    int quad = lane >> 4;
    float* sp = states + (size_t)bx * 4096;
    #pragma unroll
    for (int dt = 0; dt < 4; dt++)
        #pragma unroll
        for (int reg = 0; reg < 4; reg++)
            sp[(band + quad * 4 + reg) * 64 + dt * 16 + mrel] = acc[dt][reg];
}

__global__ __launch_bounds__(256) void prefix_kernel(const float* __restrict__ states,
                                                     ushort* __restrict__ statesb) {
    int bh = blockIdx.y;
    int e = blockIdx.x * 256 + threadIdx.x;
    const float* src = states + (size_t)bh * NCHUNK * 4096 + e;
    ushort* dst = statesb + (size_t)bh * NCHUNK * 4096 + e;
    float run = 0.f;
    for (int cb = 0; cb < NCHUNK; cb += 8) {
        float vals[8];
        #pragma unroll
        for (int u = 0; u < 8; u++) vals[u] = src[(size_t)(cb + u) * 4096];
        #pragma unroll
        for (int u = 0; u < 8; u++) {
            dst[(size_t)(cb + u) * 4096] = f2bf(run);
            run += vals[u];
        }
    }
}

__global__ __launch_bounds__(256) void attn_mfma(const ushort* __restrict__ qp,
                                                 const ushort* __restrict__ kp,
                                                 const ushort* __restrict__ vp,
                                                 const ushort* __restrict__ statesb,
                                                 ushort* __restrict__ attn_out) {
    __shared__ ushort Qs[64 * LT];
    __shared__ ushort Ks[64 * LT];
    __shared__ ushort Vt[64 * LT];
    __shared__ ushort St[64 * LT];
    __shared__ ushort Ps[64 * LT];
    int bx = blockIdx.x;
    int c = bx & 31, h = (bx >> 5) & 15, b = bx >> 9;
    int t = threadIdx.x, lane = t & 63, w = t >> 6;
    size_t rowbase = (size_t)(b * SEQ + c * 64);
    int r = t >> 2, cc = t & 3;
    {
        const uint4* gq = (const uint4*)(qp + (rowbase + r) * D_MODEL + h * 64 + cc * 16);
        const uint4* gk = (const uint4*)(kp + (rowbase + r) * D_MODEL + h * 64 + cc * 16);
        const uint4* gv = (const uint4*)(vp + (rowbase + r) * D_MODEL + h * 64 + cc * 16);
        const uint4* gs = (const uint4*)(statesb + (size_t)bx * 4096 + t * 16);
        uint4 q0 = gq[0], q1 = gq[1];
        uint4 k0 = gk[0], k1 = gk[1];
        uint4 v0 = gv[0], v1 = gv[1];
        uint4 s0 = gs[0], s1 = gs[1];
        st16(&Qs[r * LT + cc * 16], q0, q1);
        st16(&Ks[r * LT + cc * 16], k0, k1);
        st16(&St[r * LT + cc * 16], s0, s1);
        us16x8 va = __builtin_bit_cast(us16x8, v0), vb = __builtin_bit_cast(us16x8, v1);
        #pragma unroll
        for (int i = 0; i < 8; i++) {
            Vt[(cc * 16 + i) * LT + r]     = va[i];
            Vt[(cc * 16 + 8 + i) * LT + r] = vb[i];
        }
    }
    __syncthreads();

    int mrel = lane & 15, q8 = (lane >> 4) * 8, quad = lane >> 4, band = w * 16;
    bf16x8 af[2];
    af[0] = ld_frag(&Qs[(band + mrel) * LT + q8]);
    af[1] = ld_frag(&Qs[(band + mrel) * LT + 32 + q8]);

    f32x4 oacc[4];
    #pragma unroll
    for (int dt = 0; dt < 4; dt++) oacc[dt] = (f32x4){0.f, 0.f, 0.f, 0.f};
    #pragma unroll
    for (int dt = 0; dt < 4; dt++)
        #pragma unroll
        for (int kk = 0; kk < 2; kk++)
            oacc[dt] = __builtin_amdgcn_mfma_f32_16x16x32_bf16(
                af[kk], ld_frag(&St[(dt * 16 + mrel) * LT + kk * 32 + q8]), oacc[dt], 0, 0, 0);

    f32x4 pacc[4];
    #pragma unroll
    for (int jt = 0; jt < 4; jt++) pacc[jt] = (f32x4){0.f, 0.f, 0.f, 0.f};
    #pragma unroll
    for (int jt = 0; jt < 4; jt++) {
        if (jt <= w) {
            #pragma unroll
            for (int kk = 0; kk < 2; kk++)
                pacc[jt] = __builtin_amdgcn_mfma_f32_16x16x32_bf16(
                    af[kk], ld_frag(&Ks[(jt * 16 + mrel) * LT + kk * 32 + q8]), pacc[jt], 0, 0, 0);
        }
    }
    #pragma unroll
    for (int jt = 0; jt < 4; jt++) {
        #pragma unroll
        for (int reg = 0; reg < 4; reg++) {
            int i = band + quad * 4 + reg;
            int j = jt * 16 + mrel;
            float val = (jt <= w && j <= i) ? pacc[jt][reg] : 0.f;
            Ps[i * LT + j] = f2bf(val);
        }
    }
    __syncthreads();

    bf16x8 pf0 = ld_frag(&Ps[(band + mrel) * LT + q8]);
    #pragma unroll
    for (int dt = 0; dt < 4; dt++)
        oacc[dt] = __builtin_amdgcn_mfma_f32_16x16x32_bf16(
            pf0, ld_frag(&Vt[(dt * 16 + mrel) * LT + q8]), oacc[dt], 0, 0, 0);
    if (w >= 2) {
        bf16x8 pf1 = ld_frag(&Ps[(band + mrel) * LT + 32 + q8]);
        #pragma unroll
        for (int dt = 0; dt < 4; dt++)
            oacc[dt] = __builtin_amdgcn_mfma_f32_16x16x32_bf16(
                pf1, ld_frag(&Vt[(dt * 16 + mrel) * LT + 32 + q8]), oacc[dt], 0, 0, 0);
    }

    #pragma unroll
    for (int dt = 0; dt < 4; dt++) {
        #pragma unroll
        for (int reg = 0; reg < 4; reg++) {
            size_t row = rowbase + band + quad * 4 + reg;
            int col = h * 64 + dt * 16 + mrel;
            attn_out[row * D_MODEL + col] = f2bf(oacc[dt][reg]);
        }
    }
}

// ---------------- host launch ----------------
extern "C" void kernel_launch(void* const* d_in, const int* in_sizes, int n_in,
                              void* d_out, int out_size, void* d_ws, size_t ws_size,
                              hipStream_t stream) {
    (void)in_sizes; (void)n_in; (void)out_size; (void)ws_size;
    const float* x  = (const float*)d_in[0];
    const float* Wq = (const float*)d_in[1];
    const float* bq = (const float*)d_in[2];
    const float* Wk = (const float*)d_in[3];
    const float* bk = (const float*)d_in[4];
    const float* Wv = (const float*)d_in[5];
    const float* bv = (const float*)d_in[6];
    const float* Wo = (const float*)d_in[7];
    const float* bo = (const float*)d_in[8];
    const float* gamma = (const float*)d_in[9];
    float* out = (float*)d_out;

    uint8_t* w = (uint8_t*)d_ws;
    ushort* xb    = (ushort*)w; w += (size_t)XN * 2;            // 8 MB; reused as bf16 attn
    ushort* wqkvb = (ushort*)w; w += (size_t)3 * WN * 2;        // 6 MB
    ushort* wob   = (ushort*)w; w += (size_t)WN * 2;            // 2 MB
    ushort* qb  = (ushort*)w; w += (size_t)XN * 2;              // 8 MB
    ushort* kb  = (ushort*)w; w += (size_t)XN * 2;
    ushort* vb  = (ushort*)w; w += (size_t)XN * 2;
    float*  states  = (float*)w;  w += (size_t)BATCH * NUM_HEADS * NCHUNK * 4096 * 4; // 16 MB (fallback only)
    ushort* statesb = (ushort*)w; w += (size_t)BATCH * NUM_HEADS * NCHUNK * 4096 * 2; // 8 MB
    float*  decay   = (float*)w;  w += (size_t)SEQ * NUM_HEADS * 4;

    cast_all_kernel<<<CAST_BLOCKS + (SEQ * NUM_HEADS) / 256, 256, 0, stream>>>(
        x, Wq, Wk, Wv, Wo, xb, gamma, decay);

    // fused QKV projection: Bt = [Wq|Wk|Wv] (3072 x 1024), bf16 out, decay folded into q
    gemm128<3, 1><<<dim3(3072 / 128, M_TOT / 128), 256, 0, stream>>>(
        xb, wqkvb, bq, bk, bv, qb, kb, vb, decay);

    int nblk = BATCH * NUM_HEADS * NCHUNK;  // 1024 = 4 blocks/CU x 256 CU
    {
        const ushort* a0 = qb; const ushort* a1 = kb; const ushort* a2 = vb;
        ushort* a3 = statesb; ushort* a4 = xb;
        void* args[] = {&a0, &a1, &a2, &a3, &a4};
        hipError_t rc = hipLaunchCooperativeKernel((void*)fused_attn, dim3(nblk), dim3(256),
                                                   args, 0, stream);
        if (rc != hipSuccess) {
            // fallback: proven 3-kernel path
            chunk_kv_mfma<<<nblk, 256, 0, stream>>>(kb, vb, states);
            prefix_kernel<<<dim3(16, 32), 256, 0, stream>>>(states, statesb);
            attn_mfma<<<nblk, 256, 0, stream>>>(qb, kb, vb, statesb, xb);
        }
    }

    // output projection: fp32 out
    gemm128<1, 0><<<dim3(1024 / 128, M_TOT / 128), 256, 0, stream>>>(
        xb, wob, bo, nullptr, nullptr, out, nullptr, nullptr, nullptr);
}

// Round 5
// 193.596 us; speedup vs baseline: 2.3298x; 2.3298x over previous
//
#include <hip/hip_runtime.h>
#include <hip/hip_bf16.h>

#define D_MODEL 1024
#define NUM_HEADS 16
#define HEAD_DIM 64
#define BATCH 2
#define SEQ 2048
#define M_TOT (BATCH*SEQ)      // 4096
#define CHUNK 64
#define NCHUNK (SEQ/CHUNK)     // 32
#define LT 68                  // LDS stride (ushorts) for attention tiles

typedef __attribute__((ext_vector_type(8))) short bf16x8;
typedef __attribute__((ext_vector_type(8))) unsigned short us16x8;
typedef __attribute__((ext_vector_type(4))) float f32x4;

__device__ inline ushort f2bf(float f) {
    __hip_bfloat16 h = __float2bfloat16(f);
    return __builtin_bit_cast(ushort, h);
}
__device__ inline float bf2f(ushort u) {
    unsigned int v = ((unsigned int)u) << 16;
    return __builtin_bit_cast(float, v);
}

__device__ inline bf16x8 ld_frag(const ushort* p) {
    struct S { uint2 a, b; };
    S s;
    s.a = *(const uint2*)p;
    s.b = *(const uint2*)(p + 4);
    return __builtin_bit_cast(bf16x8, s);
}

__device__ inline void st16(ushort* dst, uint4 a, uint4 b) {
    *(uint2*)(dst + 0)  = make_uint2(a.x, a.y);
    *(uint2*)(dst + 4)  = make_uint2(a.z, a.w);
    *(uint2*)(dst + 8)  = make_uint2(b.x, b.y);
    *(uint2*)(dst + 12) = make_uint2(b.z, b.w);
}

// async global->LDS, 16B per lane; LDS dst is wave-uniform base + lane*16
__device__ inline void load_lds16(const ushort* g, ushort* l) {
    __builtin_amdgcn_global_load_lds(
        (const __attribute__((address_space(1))) unsigned int*)g,
        (__attribute__((address_space(3))) unsigned int*)l, 16, 0, 0);
}

// ---------------- fused cast fp32 -> bf16 (x|Wq|Wk|Wv|Wo) + decay table ----------------
#define XN (M_TOT * D_MODEL)              // 4194304
#define WN (D_MODEL * D_MODEL)            // 1048576
#define CAST_BLOCKS ((XN + 4 * WN) / 4 / 256)   // 8192
__global__ __launch_bounds__(256) void cast_all_kernel(const float* __restrict__ x,
                                                       const float* __restrict__ Wq,
                                                       const float* __restrict__ Wk,
                                                       const float* __restrict__ Wv,
                                                       const float* __restrict__ Wo,
                                                       ushort* __restrict__ dst,
                                                       const float* __restrict__ gamma,
                                                       float* __restrict__ decay) {
    int bx = blockIdx.x;
    if (bx >= CAST_BLOCKS) {  // decay region: gamma[h]^i
        int idx = (bx - CAST_BLOCKS) * 256 + threadIdx.x;   // 32768 total
        int i = idx >> 4, h = idx & 15;
        decay[idx] = powf(gamma[h], (float)i);
        return;
    }
    size_t o = ((size_t)bx * 256 + threadIdx.x) * 4;
    const float* src;
    if (o < XN)               src = x  + o;
    else if (o < XN + WN)     src = Wq + (o - XN);
    else if (o < XN + 2 * WN) src = Wk + (o - XN - WN);
    else if (o < XN + 3 * WN) src = Wv + (o - XN - 2 * (size_t)WN);
    else                      src = Wo + (o - XN - 3 * (size_t)WN);
    float4 f = *(const float4*)src;
    ushort4 u;
    u.x = f2bf(f.x); u.y = f2bf(f.y); u.z = f2bf(f.z); u.w = f2bf(f.w);
    *(ushort4*)(dst + o) = u;
}

// ---------------- 128x128-tile MFMA GEMM, global_load_lds staging, XOR-swizzled LDS ----
// XCD-aware block remap: linear p -> xcd = p%8 owns gridDim.x/8 B-columns, so each
// XCD's L2 holds a small resident B slice while A streams (cuts B re-fetch ~5x).
template <int NBUF, int OUT_BF16>
__global__ __launch_bounds__(256) void gemm128(const ushort* __restrict__ A,
                                               const ushort* __restrict__ Bt,
                                               const float* __restrict__ b0,
                                               const float* __restrict__ b1,
                                               const float* __restrict__ b2,
                                               void* __restrict__ o0,
                                               void* __restrict__ o1,
                                               void* __restrict__ o2,
                                               const float* __restrict__ decay) {
    const int K = 1024;
    __shared__ ushort lds_a[128 * 64];   // 16 KB, row-major, chunk-col XOR-swizzled
    __shared__ ushort lds_b[128 * 64];
    int t = threadIdx.x;
    int lane = t & 63, w = t >> 6;

    int p = blockIdx.y * gridDim.x + blockIdx.x;
    int xcd = p & 7, q = p >> 3;
    int cpx = gridDim.x >> 3;           // B-columns per XCD (3 for QKV, 1 for Wo)
    int bn = (xcd * cpx + (q % cpx)) * 128;
    int bm = (q / cpx) * 128;
    int wm = (w >> 1) * 64, wn = (w & 1) * 64;

    int lr = lane >> 3, lc = lane & 7;
    int gcol = lc ^ (lr & 7);
    const ushort* aBase = A  + (size_t)(bm + w * 32 + lr) * K + gcol * 8;
    const ushort* bBase = Bt + (size_t)(bn + w * 32 + lr) * K + gcol * 8;
    ushort* aLds = &lds_a[(w * 32) * 64];
    ushort* bLds = &lds_b[(w * 32) * 64];

    f32x4 acc[4][4];
    #pragma unroll
    for (int i = 0; i < 4; i++)
        #pragma unroll
        for (int j = 0; j < 4; j++)
            acc[i][j] = (f32x4){0.f, 0.f, 0.f, 0.f};

    int mrel = lane & 15, kq = lane >> 4;

    for (int k0 = 0; k0 < K; k0 += 64) {
        #pragma unroll
        for (int qq = 0; qq < 4; qq++) {
            load_lds16(aBase + (size_t)qq * 8 * K + k0, aLds + qq * 512);
            load_lds16(bBase + (size_t)qq * 8 * K + k0, bLds + qq * 512);
        }
        __syncthreads();
        #pragma unroll
        for (int s = 0; s < 2; s++) {
            bf16x8 af[4], bfv[4];
            #pragma unroll
            for (int i = 0; i < 4; i++) {
                int row = wm + i * 16 + mrel;
                af[i] = ld_frag(&lds_a[row * 64 + (((s * 4 + kq) ^ (row & 7)) * 8)]);
            }
            #pragma unroll
            for (int j = 0; j < 4; j++) {
                int row = wn + j * 16 + mrel;
                bfv[j] = ld_frag(&lds_b[row * 64 + (((s * 4 + kq) ^ (row & 7)) * 8)]);
            }
            #pragma unroll
            for (int i = 0; i < 4; i++)
                #pragma unroll
                for (int j = 0; j < 4; j++)
                    acc[i][j] = __builtin_amdgcn_mfma_f32_16x16x32_bf16(af[i], bfv[j], acc[i][j], 0, 0, 0);
        }
        __syncthreads();
    }

    int quad = lane >> 4;
    int buf = (NBUF == 3) ? (bn >> 10) : 0;
    const float* bias = (buf == 0) ? b0 : (buf == 1) ? b1 : b2;
    void* dstv = (buf == 0) ? o0 : (buf == 1) ? o1 : o2;
    int cbase = ((NBUF == 3) ? (bn & 1023) : bn) + wn;
    #pragma unroll
    for (int j = 0; j < 4; j++) {
        int cl = cbase + j * 16 + mrel;
        float bv = bias[cl];
        #pragma unroll
        for (int i = 0; i < 4; i++) {
            #pragma unroll
            for (int reg = 0; reg < 4; reg++) {
                int row = bm + wm + i * 16 + quad * 4 + reg;
                float v = acc[i][j][reg] + bv;
                if (NBUF == 3 && buf == 0)
                    v *= decay[(row & (SEQ - 1)) * 16 + (cl >> 6)];
                if (OUT_BF16)
                    ((ushort*)dstv)[(size_t)row * 1024 + cl] = f2bf(v);
                else
                    ((float*)dstv)[(size_t)row * 1024 + cl] = v;
            }
        }
    }
}

// ---------------- per-chunk KV state (MFMA) -> bf16, coalesced via LDS ----------------
// St[dv][dk] = sum_j V[j][dv]*K[j][dk].  grid = 1024 blocks ((b*16+h)*32 + c).
__global__ __launch_bounds__(256) void chunk_kv_mfma(const ushort* __restrict__ kp,
                                                     const ushort* __restrict__ vp,
                                                     ushort* __restrict__ statesb) {
    __shared__ ushort Kt[64 * LT];
    __shared__ ushort Vt[64 * LT];
    int bx = blockIdx.x;
    int c = bx & 31, h = (bx >> 5) & 15, b = bx >> 9;
    int t = threadIdx.x, lane = t & 63, w = t >> 6;
    size_t rowbase = (size_t)(b * SEQ + c * 64);
    int r = t >> 2, cc = t & 3;
    const uint4* gk = (const uint4*)(kp + (rowbase + r) * D_MODEL + h * 64 + cc * 16);
    const uint4* gv = (const uint4*)(vp + (rowbase + r) * D_MODEL + h * 64 + cc * 16);
    uint4 k0 = gk[0], k1 = gk[1], v0 = gv[0], v1 = gv[1];
    {
        us16x8 ka = __builtin_bit_cast(us16x8, k0), kb = __builtin_bit_cast(us16x8, k1);
        us16x8 va = __builtin_bit_cast(us16x8, v0), vb = __builtin_bit_cast(us16x8, v1);
        #pragma unroll
        for (int i = 0; i < 8; i++) {
            Kt[(cc * 16 + i) * LT + r]     = ka[i];
            Kt[(cc * 16 + 8 + i) * LT + r] = kb[i];
            Vt[(cc * 16 + i) * LT + r]     = va[i];
            Vt[(cc * 16 + 8 + i) * LT + r] = vb[i];
        }
    }
    __syncthreads();
    int mrel = lane & 15, q8 = (lane >> 4) * 8, band = w * 16, quad = lane >> 4;
    bf16x8 af[2];
    af[0] = ld_frag(&Vt[(band + mrel) * LT + q8]);
    af[1] = ld_frag(&Vt[(band + mrel) * LT + 32 + q8]);
    f32x4 acc[4];
    #pragma unroll
    for (int dt = 0; dt < 4; dt++) acc[dt] = (f32x4){0.f, 0.f, 0.f, 0.f};
    #pragma unroll
    for (int dt = 0; dt < 4; dt++)
        #pragma unroll
        for (int kk = 0; kk < 2; kk++)
            acc[dt] = __builtin_amdgcn_mfma_f32_16x16x32_bf16(
                af[kk], ld_frag(&Kt[(dt * 16 + mrel) * LT + kk * 32 + q8]), acc[dt], 0, 0, 0);
    __syncthreads();   // all waves done reading Kt/Vt
    // bf16 via LDS (reuse Kt) for coalesced global store
    #pragma unroll
    for (int dt = 0; dt < 4; dt++)
        #pragma unroll
        for (int reg = 0; reg < 4; reg++)
            Kt[(band + quad * 4 + reg) * LT + dt * 16 + mrel] = f2bf(acc[dt][reg]);
    __syncthreads();
    {
        bf16x8 s0 = ld_frag(&Kt[r * LT + cc * 16]);
        bf16x8 s1 = ld_frag(&Kt[r * LT + cc * 16 + 8]);
        uint4* dst = (uint4*)(statesb + (size_t)bx * 4096 + r * 64 + cc * 16);
        dst[0] = __builtin_bit_cast(uint4, s0);
        dst[1] = __builtin_bit_cast(uint4, s1);
    }
}

// ---------------- exclusive prefix over chunks, bf16 in place ----------------
// grid (16, 32): blockIdx.y = bh; each thread scans one of 4096 state elements.
__global__ __launch_bounds__(256) void prefix_kernel(ushort* __restrict__ statesb) {
    int bh = blockIdx.y;
    int e = blockIdx.x * 256 + threadIdx.x;
    ushort* p = statesb + (size_t)bh * NCHUNK * 4096 + e;
    float run = 0.f;
    for (int cb = 0; cb < NCHUNK; cb += 8) {
        float vals[8];
        #pragma unroll
        for (int u = 0; u < 8; u++) vals[u] = bf2f(p[(size_t)(cb + u) * 4096]);
        #pragma unroll
        for (int u = 0; u < 8; u++) {
            p[(size_t)(cb + u) * 4096] = f2bf(run);
            run += vals[u];
        }
    }
}

// ---------------- per-chunk attention (MFMA): O = Q'·S^T + causal(Q'K^T)·V ----------------
__global__ __launch_bounds__(256) void attn_mfma(const ushort* __restrict__ qp,
                                                 const ushort* __restrict__ kp,
                                                 const ushort* __restrict__ vp,
                                                 const ushort* __restrict__ statesb,
                                                 ushort* __restrict__ attn_out) {
    __shared__ ushort Qs[64 * LT];
    __shared__ ushort Ks[64 * LT];
    __shared__ ushort Vt[64 * LT];
    __shared__ ushort St[64 * LT];
    __shared__ ushort Ps[64 * LT];
    int bx = blockIdx.x;
    int c = bx & 31, h = (bx >> 5) & 15, b = bx >> 9;
    int t = threadIdx.x, lane = t & 63, w = t >> 6;
    size_t rowbase = (size_t)(b * SEQ + c * 64);
    int r = t >> 2, cc = t & 3;
    {
        const uint4* gq = (const uint4*)(qp + (rowbase + r) * D_MODEL + h * 64 + cc * 16);
        const uint4* gk = (const uint4*)(kp + (rowbase + r) * D_MODEL + h * 64 + cc * 16);
        const uint4* gv = (const uint4*)(vp + (rowbase + r) * D_MODEL + h * 64 + cc * 16);
        const uint4* gs = (const uint4*)(statesb + (size_t)bx * 4096 + t * 16);
        uint4 q0 = gq[0], q1 = gq[1];
        uint4 k0 = gk[0], k1 = gk[1];
        uint4 v0 = gv[0], v1 = gv[1];
        uint4 s0 = gs[0], s1 = gs[1];
        st16(&Qs[r * LT + cc * 16], q0, q1);
        st16(&Ks[r * LT + cc * 16], k0, k1);
        st16(&St[r * LT + cc * 16], s0, s1);
        us16x8 va = __builtin_bit_cast(us16x8, v0), vb = __builtin_bit_cast(us16x8, v1);
        #pragma unroll
        for (int i = 0; i < 8; i++) {
            Vt[(cc * 16 + i) * LT + r]     = va[i];
            Vt[(cc * 16 + 8 + i) * LT + r] = vb[i];
        }
    }
    __syncthreads();

    int mrel = lane & 15, q8 = (lane >> 4) * 8, quad = lane >> 4, band = w * 16;
    bf16x8 af[2];
    af[0] = ld_frag(&Qs[(band + mrel) * LT + q8]);
    af[1] = ld_frag(&Qs[(band + mrel) * LT + 32 + q8]);

    f32x4 oacc[4];
    #pragma unroll
    for (int dt = 0; dt < 4; dt++) oacc[dt] = (f32x4){0.f, 0.f, 0.f, 0.f};
    #pragma unroll
    for (int dt = 0; dt < 4; dt++)
        #pragma unroll
        for (int kk = 0; kk < 2; kk++)
            oacc[dt] = __builtin_amdgcn_mfma_f32_16x16x32_bf16(
                af[kk], ld_frag(&St[(dt * 16 + mrel) * LT + kk * 32 + q8]), oacc[dt], 0, 0, 0);

    f32x4 pacc[4];
    #pragma unroll
    for (int jt = 0; jt < 4; jt++) pacc[jt] = (f32x4){0.f, 0.f, 0.f, 0.f};
    #pragma unroll
    for (int jt = 0; jt < 4; jt++) {
        if (jt <= w) {
            #pragma unroll
            for (int kk = 0; kk < 2; kk++)
                pacc[jt] = __builtin_amdgcn_mfma_f32_16x16x32_bf16(
                    af[kk], ld_frag(&Ks[(jt * 16 + mrel) * LT + kk * 32 + q8]), pacc[jt], 0, 0, 0);
        }
    }
    #pragma unroll
    for (int jt = 0; jt < 4; jt++) {
        #pragma unroll
        for (int reg = 0; reg < 4; reg++) {
            int i = band + quad * 4 + reg;
            int j = jt * 16 + mrel;
            float val = (jt <= w && j <= i) ? pacc[jt][reg] : 0.f;
            Ps[i * LT + j] = f2bf(val);
        }
    }
    __syncthreads();

    bf16x8 pf0 = ld_frag(&Ps[(band + mrel) * LT + q8]);
    #pragma unroll
    for (int dt = 0; dt < 4; dt++)
        oacc[dt] = __builtin_amdgcn_mfma_f32_16x16x32_bf16(
            pf0, ld_frag(&Vt[(dt * 16 + mrel) * LT + q8]), oacc[dt], 0, 0, 0);
    if (w >= 2) {
        bf16x8 pf1 = ld_frag(&Ps[(band + mrel) * LT + 32 + q8]);
        #pragma unroll
        for (int dt = 0; dt < 4; dt++)
            oacc[dt] = __builtin_amdgcn_mfma_f32_16x16x32_bf16(
                pf1, ld_frag(&Vt[(dt * 16 + mrel) * LT + 32 + q8]), oacc[dt], 0, 0, 0);
    }

    #pragma unroll
    for (int dt = 0; dt < 4; dt++) {
        #pragma unroll
        for (int reg = 0; reg < 4; reg++) {
            size_t row = rowbase + band + quad * 4 + reg;
            int col = h * 64 + dt * 16 + mrel;
            attn_out[row * D_MODEL + col] = f2bf(oacc[dt][reg]);
        }
    }
}

// ---------------- host launch ----------------
extern "C" void kernel_launch(void* const* d_in, const int* in_sizes, int n_in,
                              void* d_out, int out_size, void* d_ws, size_t ws_size,
                              hipStream_t stream) {
    (void)in_sizes; (void)n_in; (void)out_size; (void)ws_size;
    const float* x  = (const float*)d_in[0];
    const float* Wq = (const float*)d_in[1];
    const float* bq = (const float*)d_in[2];
    const float* Wk = (const float*)d_in[3];
    const float* bk = (const float*)d_in[4];
    const float* Wv = (const float*)d_in[5];
    const float* bv = (const float*)d_in[6];
    const float* Wo = (const float*)d_in[7];
    const float* bo = (const float*)d_in[8];
    const float* gamma = (const float*)d_in[9];
    float* out = (float*)d_out;

    uint8_t* w = (uint8_t*)d_ws;
    ushort* xb    = (ushort*)w; w += (size_t)XN * 2;            // 8 MB; reused as bf16 attn
    ushort* wqkvb = (ushort*)w; w += (size_t)3 * WN * 2;        // 6 MB
    ushort* wob   = (ushort*)w; w += (size_t)WN * 2;            // 2 MB
    ushort* qb  = (ushort*)w; w += (size_t)XN * 2;              // 8 MB
    ushort* kb  = (ushort*)w; w += (size_t)XN * 2;
    ushort* vb  = (ushort*)w; w += (size_t)XN * 2;
    ushort* statesb = (ushort*)w; w += (size_t)BATCH * NUM_HEADS * NCHUNK * 4096 * 2; // 8 MB
    float*  decay   = (float*)w;  w += (size_t)SEQ * NUM_HEADS * 4;

    cast_all_kernel<<<CAST_BLOCKS + (SEQ * NUM_HEADS) / 256, 256, 0, stream>>>(
        x, Wq, Wk, Wv, Wo, xb, gamma, decay);

    // fused QKV projection: Bt = [Wq|Wk|Wv] (3072 x 1024), bf16 out, decay folded into q
    gemm128<3, 1><<<dim3(3072 / 128, M_TOT / 128), 256, 0, stream>>>(
        xb, wqkvb, bq, bk, bv, qb, kb, vb, decay);

    int nblk = BATCH * NUM_HEADS * NCHUNK;  // 1024
    chunk_kv_mfma<<<nblk, 256, 0, stream>>>(kb, vb, statesb);
    prefix_kernel<<<dim3(16, 32), 256, 0, stream>>>(statesb);
    attn_mfma<<<nblk, 256, 0, stream>>>(qb, kb, vb, statesb, xb);   // bf16 attn into xb

    // output projection: fp32 out
    gemm128<1, 0><<<dim3(1024 / 128, M_TOT / 128), 256, 0, stream>>>(
        xb, wob, bo, nullptr, nullptr, out, nullptr, nullptr, nullptr);
}

// Round 6
// 179.886 us; speedup vs baseline: 2.5074x; 1.0762x over previous
//
#include <hip/hip_runtime.h>
#include <hip/hip_bf16.h>

#define D_MODEL 1024
#define NUM_HEADS 16
#define HEAD_DIM 64
#define BATCH 2
#define SEQ 2048
#define M_TOT (BATCH*SEQ)      // 4096
#define CHUNK 64
#define NCHUNK (SEQ/CHUNK)     // 32
#define LT 68                  // LDS stride (ushorts) for attention tiles

typedef __attribute__((ext_vector_type(8))) short bf16x8;
typedef __attribute__((ext_vector_type(8))) unsigned short us16x8;
typedef __attribute__((ext_vector_type(4))) float f32x4;

__device__ inline ushort f2bf(float f) {
    __hip_bfloat16 h = __float2bfloat16(f);
    return __builtin_bit_cast(ushort, h);
}
__device__ inline float bf2f(ushort u) {
    unsigned int v = ((unsigned int)u) << 16;
    return __builtin_bit_cast(float, v);
}

__device__ inline bf16x8 ld_frag(const ushort* p) {
    struct S { uint2 a, b; };
    S s;
    s.a = *(const uint2*)p;
    s.b = *(const uint2*)(p + 4);
    return __builtin_bit_cast(bf16x8, s);
}

__device__ inline void st16(ushort* dst, uint4 a, uint4 b) {
    *(uint2*)(dst + 0)  = make_uint2(a.x, a.y);
    *(uint2*)(dst + 4)  = make_uint2(a.z, a.w);
    *(uint2*)(dst + 8)  = make_uint2(b.x, b.y);
    *(uint2*)(dst + 12) = make_uint2(b.z, b.w);
}

// async global->LDS, 16B per lane; LDS dst is wave-uniform base + lane*16
__device__ inline void load_lds16(const ushort* g, ushort* l) {
    __builtin_amdgcn_global_load_lds(
        (const __attribute__((address_space(1))) unsigned int*)g,
        (__attribute__((address_space(3))) unsigned int*)l, 16, 0, 0);
}

// ---------------- fused cast fp32 -> bf16 (x|Wq|Wk|Wv|Wo) + decay table ----------------
#define XN (M_TOT * D_MODEL)              // 4194304
#define WN (D_MODEL * D_MODEL)            // 1048576
#define CAST_BLOCKS ((XN + 4 * WN) / 4 / 256)   // 8192
__global__ __launch_bounds__(256) void cast_all_kernel(const float* __restrict__ x,
                                                       const float* __restrict__ Wq,
                                                       const float* __restrict__ Wk,
                                                       const float* __restrict__ Wv,
                                                       const float* __restrict__ Wo,
                                                       ushort* __restrict__ dst,
                                                       const float* __restrict__ gamma,
                                                       float* __restrict__ decay) {
    int bx = blockIdx.x;
    if (bx >= CAST_BLOCKS) {  // decay region: gamma[h]^i
        int idx = (bx - CAST_BLOCKS) * 256 + threadIdx.x;   // 32768 total
        int i = idx >> 4, h = idx & 15;
        decay[idx] = powf(gamma[h], (float)i);
        return;
    }
    size_t o = ((size_t)bx * 256 + threadIdx.x) * 4;
    const float* src;
    if (o < XN)               src = x  + o;
    else if (o < XN + WN)     src = Wq + (o - XN);
    else if (o < XN + 2 * WN) src = Wk + (o - XN - WN);
    else if (o < XN + 3 * WN) src = Wv + (o - XN - 2 * (size_t)WN);
    else                      src = Wo + (o - XN - 3 * (size_t)WN);
    float4 f = *(const float4*)src;
    ushort4 u;
    u.x = f2bf(f.x); u.y = f2bf(f.y); u.z = f2bf(f.z); u.w = f2bf(f.w);
    *(ushort4*)(dst + o) = u;
}

// ---------------- 128x128-tile MFMA GEMM (QKV), global_load_lds, XOR-swizzled LDS ------
// C[m,n] = sum_k A[m,k]*Bt[n,k] + bias[n]; Bt = [Wq|Wk|Wv] (3072x1024); bf16 outputs;
// decay folded into buffer 0 (q). Round-3 proven block mapping (no XCD remap).
__global__ __launch_bounds__(256) void gemm128_qkv(const ushort* __restrict__ A,
                                                   const ushort* __restrict__ Bt,
                                                   const float* __restrict__ b0,
                                                   const float* __restrict__ b1,
                                                   const float* __restrict__ b2,
                                                   ushort* __restrict__ o0,
                                                   ushort* __restrict__ o1,
                                                   ushort* __restrict__ o2,
                                                   const float* __restrict__ decay) {
    const int K = 1024;
    __shared__ ushort lds_a[128 * 64];   // 16 KB, row-major, chunk-col XOR-swizzled
    __shared__ ushort lds_b[128 * 64];
    int t = threadIdx.x;
    int lane = t & 63, w = t >> 6;
    int bm = blockIdx.y * 128, bn = blockIdx.x * 128;
    int wm = (w >> 1) * 64, wn = (w & 1) * 64;

    int lr = lane >> 3, lc = lane & 7;
    int gcol = lc ^ (lr & 7);
    const ushort* aBase = A  + (size_t)(bm + w * 32 + lr) * K + gcol * 8;
    const ushort* bBase = Bt + (size_t)(bn + w * 32 + lr) * K + gcol * 8;
    ushort* aLds = &lds_a[(w * 32) * 64];
    ushort* bLds = &lds_b[(w * 32) * 64];

    f32x4 acc[4][4];
    #pragma unroll
    for (int i = 0; i < 4; i++)
        #pragma unroll
        for (int j = 0; j < 4; j++)
            acc[i][j] = (f32x4){0.f, 0.f, 0.f, 0.f};

    int mrel = lane & 15, kq = lane >> 4;

    for (int k0 = 0; k0 < K; k0 += 64) {
        #pragma unroll
        for (int qq = 0; qq < 4; qq++) {
            load_lds16(aBase + (size_t)qq * 8 * K + k0, aLds + qq * 512);
            load_lds16(bBase + (size_t)qq * 8 * K + k0, bLds + qq * 512);
        }
        __syncthreads();
        #pragma unroll
        for (int s = 0; s < 2; s++) {
            bf16x8 af[4], bfv[4];
            #pragma unroll
            for (int i = 0; i < 4; i++) {
                int row = wm + i * 16 + mrel;
                af[i] = ld_frag(&lds_a[row * 64 + (((s * 4 + kq) ^ (row & 7)) * 8)]);
            }
            #pragma unroll
            for (int j = 0; j < 4; j++) {
                int row = wn + j * 16 + mrel;
                bfv[j] = ld_frag(&lds_b[row * 64 + (((s * 4 + kq) ^ (row & 7)) * 8)]);
            }
            #pragma unroll
            for (int i = 0; i < 4; i++)
                #pragma unroll
                for (int j = 0; j < 4; j++)
                    acc[i][j] = __builtin_amdgcn_mfma_f32_16x16x32_bf16(af[i], bfv[j], acc[i][j], 0, 0, 0);
        }
        __syncthreads();
    }

    int quad = lane >> 4;
    int buf = bn >> 10;
    const float* bias = (buf == 0) ? b0 : (buf == 1) ? b1 : b2;
    ushort* dstv = (buf == 0) ? o0 : (buf == 1) ? o1 : o2;
    int cbase = (bn & 1023) + wn;
    #pragma unroll
    for (int j = 0; j < 4; j++) {
        int cl = cbase + j * 16 + mrel;
        float bv = bias[cl];
        #pragma unroll
        for (int i = 0; i < 4; i++) {
            #pragma unroll
            for (int reg = 0; reg < 4; reg++) {
                int row = bm + wm + i * 16 + quad * 4 + reg;
                float v = acc[i][j][reg] + bv;
                if (buf == 0)
                    v *= decay[(row & (SEQ - 1)) * 16 + (cl >> 6)];
                dstv[(size_t)row * 1024 + cl] = f2bf(v);
            }
        }
    }
}

// ---------------- 64x64-tile MFMA GEMM (Wo): 1024 blocks for 4x co-residency ----------
// out[m,n] = sum_k attn[m,k]*Wo[n,k] + bo[n], fp32 out. grid (16, 64), 256 thr (4 waves).
__global__ __launch_bounds__(256) void gemm64_wo(const ushort* __restrict__ A,
                                                 const ushort* __restrict__ Bt,
                                                 const float* __restrict__ bias,
                                                 float* __restrict__ C) {
    const int K = 1024;
    __shared__ ushort lds_a[64 * 64];   // 8 KB each, XOR-swizzled chunk cols
    __shared__ ushort lds_b[64 * 64];
    int t = threadIdx.x, lane = t & 63, w = t >> 6;
    int bm = blockIdx.y * 64, bn = blockIdx.x * 64;
    int wm = (w >> 1) * 32, wn = (w & 1) * 32;

    int lr = lane >> 3, lc = lane & 7;
    int gcol = lc ^ (lr & 7);
    // wave w stages A rows [w*16, w*16+16) and B rows [w*16, w*16+16)
    const ushort* aBase = A  + (size_t)(bm + w * 16 + lr) * K + gcol * 8;
    const ushort* bBase = Bt + (size_t)(bn + w * 16 + lr) * K + gcol * 8;
    ushort* aLds = &lds_a[(w * 16) * 64];
    ushort* bLds = &lds_b[(w * 16) * 64];

    f32x4 acc[2][2];
    #pragma unroll
    for (int i = 0; i < 2; i++)
        #pragma unroll
        for (int j = 0; j < 2; j++)
            acc[i][j] = (f32x4){0.f, 0.f, 0.f, 0.f};

    int mrel = lane & 15, kq = lane >> 4;

    for (int k0 = 0; k0 < K; k0 += 64) {
        load_lds16(aBase + k0, aLds);
        load_lds16(aBase + (size_t)8 * K + k0, aLds + 512);
        load_lds16(bBase + k0, bLds);
        load_lds16(bBase + (size_t)8 * K + k0, bLds + 512);
        __syncthreads();
        #pragma unroll
        for (int s = 0; s < 2; s++) {
            bf16x8 af[2], bfv[2];
            #pragma unroll
            for (int i = 0; i < 2; i++) {
                int row = wm + i * 16 + mrel;
                af[i] = ld_frag(&lds_a[row * 64 + (((s * 4 + kq) ^ (row & 7)) * 8)]);
            }
            #pragma unroll
            for (int j = 0; j < 2; j++) {
                int row = wn + j * 16 + mrel;
                bfv[j] = ld_frag(&lds_b[row * 64 + (((s * 4 + kq) ^ (row & 7)) * 8)]);
            }
            #pragma unroll
            for (int i = 0; i < 2; i++)
                #pragma unroll
                for (int j = 0; j < 2; j++)
                    acc[i][j] = __builtin_amdgcn_mfma_f32_16x16x32_bf16(af[i], bfv[j], acc[i][j], 0, 0, 0);
        }
        __syncthreads();
    }

    int quad = lane >> 4;
    #pragma unroll
    for (int j = 0; j < 2; j++) {
        int col = bn + wn + j * 16 + mrel;
        float bv = bias[col];
        #pragma unroll
        for (int i = 0; i < 2; i++) {
            #pragma unroll
            for (int reg = 0; reg < 4; reg++) {
                int row = bm + wm + i * 16 + quad * 4 + reg;
                C[(size_t)row * 1024 + col] = acc[i][j][reg] + bv;
            }
        }
    }
}

// ---------------- per-chunk KV state (MFMA) -> bf16, coalesced via LDS ----------------
__global__ __launch_bounds__(256) void chunk_kv_mfma(const ushort* __restrict__ kp,
                                                     const ushort* __restrict__ vp,
                                                     ushort* __restrict__ statesb) {
    __shared__ ushort Kt[64 * LT];
    __shared__ ushort Vt[64 * LT];
    int bx = blockIdx.x;
    int c = bx & 31, h = (bx >> 5) & 15, b = bx >> 9;
    int t = threadIdx.x, lane = t & 63, w = t >> 6;
    size_t rowbase = (size_t)(b * SEQ + c * 64);
    int r = t >> 2, cc = t & 3;
    const uint4* gk = (const uint4*)(kp + (rowbase + r) * D_MODEL + h * 64 + cc * 16);
    const uint4* gv = (const uint4*)(vp + (rowbase + r) * D_MODEL + h * 64 + cc * 16);
    uint4 k0 = gk[0], k1 = gk[1], v0 = gv[0], v1 = gv[1];
    {
        us16x8 ka = __builtin_bit_cast(us16x8, k0), kb = __builtin_bit_cast(us16x8, k1);
        us16x8 va = __builtin_bit_cast(us16x8, v0), vb = __builtin_bit_cast(us16x8, v1);
        #pragma unroll
        for (int i = 0; i < 8; i++) {
            Kt[(cc * 16 + i) * LT + r]     = ka[i];
            Kt[(cc * 16 + 8 + i) * LT + r] = kb[i];
            Vt[(cc * 16 + i) * LT + r]     = va[i];
            Vt[(cc * 16 + 8 + i) * LT + r] = vb[i];
        }
    }
    __syncthreads();
    int mrel = lane & 15, q8 = (lane >> 4) * 8, band = w * 16, quad = lane >> 4;
    bf16x8 af[2];
    af[0] = ld_frag(&Vt[(band + mrel) * LT + q8]);
    af[1] = ld_frag(&Vt[(band + mrel) * LT + 32 + q8]);
    f32x4 acc[4];
    #pragma unroll
    for (int dt = 0; dt < 4; dt++) acc[dt] = (f32x4){0.f, 0.f, 0.f, 0.f};
    #pragma unroll
    for (int dt = 0; dt < 4; dt++)
        #pragma unroll
        for (int kk = 0; kk < 2; kk++)
            acc[dt] = __builtin_amdgcn_mfma_f32_16x16x32_bf16(
                af[kk], ld_frag(&Kt[(dt * 16 + mrel) * LT + kk * 32 + q8]), acc[dt], 0, 0, 0);
    __syncthreads();   // all waves done reading Kt/Vt
    #pragma unroll
    for (int dt = 0; dt < 4; dt++)
        #pragma unroll
        for (int reg = 0; reg < 4; reg++)
            Kt[(band + quad * 4 + reg) * LT + dt * 16 + mrel] = f2bf(acc[dt][reg]);
    __syncthreads();
    {
        bf16x8 s0 = ld_frag(&Kt[r * LT + cc * 16]);
        bf16x8 s1 = ld_frag(&Kt[r * LT + cc * 16 + 8]);
        uint4* dst = (uint4*)(statesb + (size_t)bx * 4096 + r * 64 + cc * 16);
        dst[0] = __builtin_bit_cast(uint4, s0);
        dst[1] = __builtin_bit_cast(uint4, s1);
    }
}

// ---------------- exclusive prefix over chunks, bf16 in place ----------------
__global__ __launch_bounds__(256) void prefix_kernel(ushort* __restrict__ statesb) {
    int bh = blockIdx.y;
    int e = blockIdx.x * 256 + threadIdx.x;
    ushort* p = statesb + (size_t)bh * NCHUNK * 4096 + e;
    float run = 0.f;
    for (int cb = 0; cb < NCHUNK; cb += 8) {
        float vals[8];
        #pragma unroll
        for (int u = 0; u < 8; u++) vals[u] = bf2f(p[(size_t)(cb + u) * 4096]);
        #pragma unroll
        for (int u = 0; u < 8; u++) {
            p[(size_t)(cb + u) * 4096] = f2bf(run);
            run += vals[u];
        }
    }
}

// ---------------- per-chunk attention (MFMA): O = Q'·S^T + causal(Q'K^T)·V ----------------
__global__ __launch_bounds__(256) void attn_mfma(const ushort* __restrict__ qp,
                                                 const ushort* __restrict__ kp,
                                                 const ushort* __restrict__ vp,
                                                 const ushort* __restrict__ statesb,
                                                 ushort* __restrict__ attn_out) {
    __shared__ ushort Qs[64 * LT];
    __shared__ ushort Ks[64 * LT];
    __shared__ ushort Vt[64 * LT];
    __shared__ ushort St[64 * LT];
    __shared__ ushort Ps[64 * LT];
    int bx = blockIdx.x;
    int c = bx & 31, h = (bx >> 5) & 15, b = bx >> 9;
    int t = threadIdx.x, lane = t & 63, w = t >> 6;
    size_t rowbase = (size_t)(b * SEQ + c * 64);
    int r = t >> 2, cc = t & 3;
    {
        const uint4* gq = (const uint4*)(qp + (rowbase + r) * D_MODEL + h * 64 + cc * 16);
        const uint4* gk = (const uint4*)(kp + (rowbase + r) * D_MODEL + h * 64 + cc * 16);
        const uint4* gv = (const uint4*)(vp + (rowbase + r) * D_MODEL + h * 64 + cc * 16);
        const uint4* gs = (const uint4*)(statesb + (size_t)bx * 4096 + t * 16);
        uint4 q0 = gq[0], q1 = gq[1];
        uint4 k0 = gk[0], k1 = gk[1];
        uint4 v0 = gv[0], v1 = gv[1];
        uint4 s0 = gs[0], s1 = gs[1];
        st16(&Qs[r * LT + cc * 16], q0, q1);
        st16(&Ks[r * LT + cc * 16], k0, k1);
        st16(&St[r * LT + cc * 16], s0, s1);
        us16x8 va = __builtin_bit_cast(us16x8, v0), vb = __builtin_bit_cast(us16x8, v1);
        #pragma unroll
        for (int i = 0; i < 8; i++) {
            Vt[(cc * 16 + i) * LT + r]     = va[i];
            Vt[(cc * 16 + 8 + i) * LT + r] = vb[i];
        }
    }
    __syncthreads();

    int mrel = lane & 15, q8 = (lane >> 4) * 8, quad = lane >> 4, band = w * 16;
    bf16x8 af[2];
    af[0] = ld_frag(&Qs[(band + mrel) * LT + q8]);
    af[1] = ld_frag(&Qs[(band + mrel) * LT + 32 + q8]);

    f32x4 oacc[4];
    #pragma unroll
    for (int dt = 0; dt < 4; dt++) oacc[dt] = (f32x4){0.f, 0.f, 0.f, 0.f};
    #pragma unroll
    for (int dt = 0; dt < 4; dt++)
        #pragma unroll
        for (int kk = 0; kk < 2; kk++)
            oacc[dt] = __builtin_amdgcn_mfma_f32_16x16x32_bf16(
                af[kk], ld_frag(&St[(dt * 16 + mrel) * LT + kk * 32 + q8]), oacc[dt], 0, 0, 0);

    f32x4 pacc[4];
    #pragma unroll
    for (int jt = 0; jt < 4; jt++) pacc[jt] = (f32x4){0.f, 0.f, 0.f, 0.f};
    #pragma unroll
    for (int jt = 0; jt < 4; jt++) {
        if (jt <= w) {
            #pragma unroll
            for (int kk = 0; kk < 2; kk++)
                pacc[jt] = __builtin_amdgcn_mfma_f32_16x16x32_bf16(
                    af[kk], ld_frag(&Ks[(jt * 16 + mrel) * LT + kk * 32 + q8]), pacc[jt], 0, 0, 0);
        }
    }
    #pragma unroll
    for (int jt = 0; jt < 4; jt++) {
        #pragma unroll
        for (int reg = 0; reg < 4; reg++) {
            int i = band + quad * 4 + reg;
            int j = jt * 16 + mrel;
            float val = (jt <= w && j <= i) ? pacc[jt][reg] : 0.f;
            Ps[i * LT + j] = f2bf(val);
        }
    }
    __syncthreads();

    bf16x8 pf0 = ld_frag(&Ps[(band + mrel) * LT + q8]);
    #pragma unroll
    for (int dt = 0; dt < 4; dt++)
        oacc[dt] = __builtin_amdgcn_mfma_f32_16x16x32_bf16(
            pf0, ld_frag(&Vt[(dt * 16 + mrel) * LT + q8]), oacc[dt], 0, 0, 0);
    if (w >= 2) {
        bf16x8 pf1 = ld_frag(&Ps[(band + mrel) * LT + 32 + q8]);
        #pragma unroll
        for (int dt = 0; dt < 4; dt++)
            oacc[dt] = __builtin_amdgcn_mfma_f32_16x16x32_bf16(
                pf1, ld_frag(&Vt[(dt * 16 + mrel) * LT + 32 + q8]), oacc[dt], 0, 0, 0);
    }

    #pragma unroll
    for (int dt = 0; dt < 4; dt++) {
        #pragma unroll
        for (int reg = 0; reg < 4; reg++) {
            size_t row = rowbase + band + quad * 4 + reg;
            int col = h * 64 + dt * 16 + mrel;
            attn_out[row * D_MODEL + col] = f2bf(oacc[dt][reg]);
        }
    }
}

// ---------------- host launch ----------------
extern "C" void kernel_launch(void* const* d_in, const int* in_sizes, int n_in,
                              void* d_out, int out_size, void* d_ws, size_t ws_size,
                              hipStream_t stream) {
    (void)in_sizes; (void)n_in; (void)out_size; (void)ws_size;
    const float* x  = (const float*)d_in[0];
    const float* Wq = (const float*)d_in[1];
    const float* bq = (const float*)d_in[2];
    const float* Wk = (const float*)d_in[3];
    const float* bk = (const float*)d_in[4];
    const float* Wv = (const float*)d_in[5];
    const float* bv = (const float*)d_in[6];
    const float* Wo = (const float*)d_in[7];
    const float* bo = (const float*)d_in[8];
    const float* gamma = (const float*)d_in[9];
    float* out = (float*)d_out;

    uint8_t* w = (uint8_t*)d_ws;
    ushort* xb    = (ushort*)w; w += (size_t)XN * 2;            // 8 MB; reused as bf16 attn
    ushort* wqkvb = (ushort*)w; w += (size_t)3 * WN * 2;        // 6 MB
    ushort* wob   = (ushort*)w; w += (size_t)WN * 2;            // 2 MB
    ushort* qb  = (ushort*)w; w += (size_t)XN * 2;              // 8 MB
    ushort* kb  = (ushort*)w; w += (size_t)XN * 2;
    ushort* vb  = (ushort*)w; w += (size_t)XN * 2;
    ushort* statesb = (ushort*)w; w += (size_t)BATCH * NUM_HEADS * NCHUNK * 4096 * 2; // 8 MB
    float*  decay   = (float*)w;  w += (size_t)SEQ * NUM_HEADS * 4;

    cast_all_kernel<<<CAST_BLOCKS + (SEQ * NUM_HEADS) / 256, 256, 0, stream>>>(
        x, Wq, Wk, Wv, Wo, xb, gamma, decay);

    // fused QKV projection: Bt = [Wq|Wk|Wv] (3072 x 1024), bf16 out, decay folded into q
    gemm128_qkv<<<dim3(3072 / 128, M_TOT / 128), 256, 0, stream>>>(
        xb, wqkvb, bq, bk, bv, qb, kb, vb, decay);

    int nblk = BATCH * NUM_HEADS * NCHUNK;  // 1024
    chunk_kv_mfma<<<nblk, 256, 0, stream>>>(kb, vb, statesb);
    prefix_kernel<<<dim3(16, 32), 256, 0, stream>>>(statesb);
    attn_mfma<<<nblk, 256, 0, stream>>>(qb, kb, vb, statesb, xb);   // bf16 attn into xb

    // output projection: 64x64 tiles -> 1024 blocks (4/CU co-residency), fp32 out
    gemm64_wo<<<dim3(1024 / 64, M_TOT / 64), 256, 0, stream>>>(xb, wob, bo, out);
}

// Round 7
// 169.306 us; speedup vs baseline: 2.6640x; 1.0625x over previous
//
#include <hip/hip_runtime.h>
#include <hip/hip_bf16.h>

#define D_MODEL 1024
#define NUM_HEADS 16
#define HEAD_DIM 64
#define BATCH 2
#define SEQ 2048
#define M_TOT (BATCH*SEQ)      // 4096
#define CHUNK 64
#define NCHUNK (SEQ/CHUNK)     // 32
#define LT 68                  // LDS stride (ushorts) for attention tiles

typedef __attribute__((ext_vector_type(8))) short bf16x8;
typedef __attribute__((ext_vector_type(8))) unsigned short us16x8;
typedef __attribute__((ext_vector_type(4))) float f32x4;

__device__ inline ushort f2bf(float f) {
    __hip_bfloat16 h = __float2bfloat16(f);
    return __builtin_bit_cast(ushort, h);
}
__device__ inline float bf2f(ushort u) {
    unsigned int v = ((unsigned int)u) << 16;
    return __builtin_bit_cast(float, v);
}

__device__ inline bf16x8 ld_frag(const ushort* p) {
    struct S { uint2 a, b; };
    S s;
    s.a = *(const uint2*)p;
    s.b = *(const uint2*)(p + 4);
    return __builtin_bit_cast(bf16x8, s);
}

__device__ inline void st16(ushort* dst, uint4 a, uint4 b) {
    *(uint2*)(dst + 0)  = make_uint2(a.x, a.y);
    *(uint2*)(dst + 4)  = make_uint2(a.z, a.w);
    *(uint2*)(dst + 8)  = make_uint2(b.x, b.y);
    *(uint2*)(dst + 12) = make_uint2(b.z, b.w);
}

// async global->LDS, 16B per lane; LDS dst is wave-uniform base + lane*16
__device__ inline void load_lds16(const ushort* g, ushort* l) {
    __builtin_amdgcn_global_load_lds(
        (const __attribute__((address_space(1))) unsigned int*)g,
        (__attribute__((address_space(3))) unsigned int*)l, 16, 0, 0);
}

// ---------------- fused cast fp32 -> bf16 (x|Wq|Wk|Wv|Wo) + decay table ----------------
#define XN (M_TOT * D_MODEL)              // 4194304
#define WN (D_MODEL * D_MODEL)            // 1048576
#define CAST_BLOCKS ((XN + 4 * WN) / 4 / 256)   // 8192
__global__ __launch_bounds__(256) void cast_all_kernel(const float* __restrict__ x,
                                                       const float* __restrict__ Wq,
                                                       const float* __restrict__ Wk,
                                                       const float* __restrict__ Wv,
                                                       const float* __restrict__ Wo,
                                                       ushort* __restrict__ dst,
                                                       const float* __restrict__ gamma,
                                                       float* __restrict__ decay) {
    int bx = blockIdx.x;
    if (bx >= CAST_BLOCKS) {  // decay region: gamma[h]^i
        int idx = (bx - CAST_BLOCKS) * 256 + threadIdx.x;   // 32768 total
        int i = idx >> 4, h = idx & 15;
        decay[idx] = powf(gamma[h], (float)i);
        return;
    }
    size_t o = ((size_t)bx * 256 + threadIdx.x) * 4;
    const float* src;
    if (o < XN)               src = x  + o;
    else if (o < XN + WN)     src = Wq + (o - XN);
    else if (o < XN + 2 * WN) src = Wk + (o - XN - WN);
    else if (o < XN + 3 * WN) src = Wv + (o - XN - 2 * (size_t)WN);
    else                      src = Wo + (o - XN - 3 * (size_t)WN);
    float4 f = *(const float4*)src;
    ushort4 u;
    u.x = f2bf(f.x); u.y = f2bf(f.y); u.z = f2bf(f.z); u.w = f2bf(f.w);
    *(ushort4*)(dst + o) = u;
}

// ---------------- 128x64-tile MFMA GEMM (QKV): 1536 blocks = 6/CU for latency hiding ---
// C[m,n] = sum_k A[m,k]*Bt[n,k] + bias[n]; Bt = [Wq|Wk|Wv] (3072x1024); bf16 outputs;
// decay folded into buffer 0 (q). grid (3072/64, 4096/128), 256 threads (4 waves, 2x2).
// Unified 192-row staging LDS (A rows 0-127, B rows 128-191), XOR-swizzled chunk cols.
__global__ __launch_bounds__(256) void gemm_qkv(const ushort* __restrict__ A,
                                                const ushort* __restrict__ Bt,
                                                const float* __restrict__ b0,
                                                const float* __restrict__ b1,
                                                const float* __restrict__ b2,
                                                ushort* __restrict__ o0,
                                                ushort* __restrict__ o1,
                                                ushort* __restrict__ o2,
                                                const float* __restrict__ decay) {
    const int K = 1024;
    __shared__ ushort lds[192 * 64];    // 24 KB: A tile (128 rows) + B tile (64 rows)
    int t = threadIdx.x;
    int lane = t & 63, w = t >> 6;
    int bn = blockIdx.x * 64, bm = blockIdx.y * 128;
    int wm = (w >> 1) * 64, wn = (w & 1) * 32;

    // staging: wave w owns rows [w*48, w*48+48) of the 192-row region, 6 slabs of 8 rows.
    int lr = lane >> 3, lc = lane & 7;
    int gcol = lc ^ (lr & 7);           // XOR swizzle: LDS chunk c holds global chunk c^(row&7)
    const ushort* gptr[6];
    int ldsoff[6];
    #pragma unroll
    for (int q = 0; q < 6; q++) {
        int grow = w * 48 + q * 8;      // wave-uniform slab base
        ldsoff[q] = grow * 64;
        int row = grow + lr;            // per-lane row within slab
        gptr[q] = (row < 128) ? (A + (size_t)(bm + row) * K + gcol * 8)
                              : (Bt + (size_t)(bn + row - 128) * K + gcol * 8);
    }

    f32x4 acc[4][2];
    #pragma unroll
    for (int i = 0; i < 4; i++)
        #pragma unroll
        for (int j = 0; j < 2; j++)
            acc[i][j] = (f32x4){0.f, 0.f, 0.f, 0.f};

    int mrel = lane & 15, kq = lane >> 4;

    for (int k0 = 0; k0 < K; k0 += 64) {
        #pragma unroll
        for (int q = 0; q < 6; q++)
            load_lds16(gptr[q] + k0, &lds[ldsoff[q]]);
        __syncthreads();
        #pragma unroll
        for (int s = 0; s < 2; s++) {
            bf16x8 af[4], bfv[2];
            #pragma unroll
            for (int i = 0; i < 4; i++) {
                int row = wm + i * 16 + mrel;
                af[i] = ld_frag(&lds[row * 64 + (((s * 4 + kq) ^ (row & 7)) * 8)]);
            }
            #pragma unroll
            for (int j = 0; j < 2; j++) {
                int row = 128 + wn + j * 16 + mrel;
                bfv[j] = ld_frag(&lds[row * 64 + (((s * 4 + kq) ^ (row & 7)) * 8)]);
            }
            #pragma unroll
            for (int i = 0; i < 4; i++)
                #pragma unroll
                for (int j = 0; j < 2; j++)
                    acc[i][j] = __builtin_amdgcn_mfma_f32_16x16x32_bf16(af[i], bfv[j], acc[i][j], 0, 0, 0);
        }
        __syncthreads();
    }

    // epilogue. C/D layout: col = lane&15, row = (lane>>4)*4 + reg
    int quad = lane >> 4;
    int buf = bn >> 10;
    const float* bias = (buf == 0) ? b0 : (buf == 1) ? b1 : b2;
    ushort* dstv = (buf == 0) ? o0 : (buf == 1) ? o1 : o2;
    int cbase = (bn & 1023) + wn;
    #pragma unroll
    for (int j = 0; j < 2; j++) {
        int cl = cbase + j * 16 + mrel;
        float bv = bias[cl];
        #pragma unroll
        for (int i = 0; i < 4; i++) {
            #pragma unroll
            for (int reg = 0; reg < 4; reg++) {
                int row = bm + wm + i * 16 + quad * 4 + reg;
                float v = acc[i][j][reg] + bv;
                if (buf == 0)
                    v *= decay[(row & (SEQ - 1)) * 16 + (cl >> 6)];
                dstv[(size_t)row * 1024 + cl] = f2bf(v);
            }
        }
    }
}

// ---------------- 64x64-tile MFMA GEMM (Wo): 1024 blocks for 4x co-residency ----------
__global__ __launch_bounds__(256) void gemm64_wo(const ushort* __restrict__ A,
                                                 const ushort* __restrict__ Bt,
                                                 const float* __restrict__ bias,
                                                 float* __restrict__ C) {
    const int K = 1024;
    __shared__ ushort lds_a[64 * 64];   // 8 KB each, XOR-swizzled chunk cols
    __shared__ ushort lds_b[64 * 64];
    int t = threadIdx.x, lane = t & 63, w = t >> 6;
    int bm = blockIdx.y * 64, bn = blockIdx.x * 64;
    int wm = (w >> 1) * 32, wn = (w & 1) * 32;

    int lr = lane >> 3, lc = lane & 7;
    int gcol = lc ^ (lr & 7);
    const ushort* aBase = A  + (size_t)(bm + w * 16 + lr) * K + gcol * 8;
    const ushort* bBase = Bt + (size_t)(bn + w * 16 + lr) * K + gcol * 8;
    ushort* aLds = &lds_a[(w * 16) * 64];
    ushort* bLds = &lds_b[(w * 16) * 64];

    f32x4 acc[2][2];
    #pragma unroll
    for (int i = 0; i < 2; i++)
        #pragma unroll
        for (int j = 0; j < 2; j++)
            acc[i][j] = (f32x4){0.f, 0.f, 0.f, 0.f};

    int mrel = lane & 15, kq = lane >> 4;

    for (int k0 = 0; k0 < K; k0 += 64) {
        load_lds16(aBase + k0, aLds);
        load_lds16(aBase + (size_t)8 * K + k0, aLds + 512);
        load_lds16(bBase + k0, bLds);
        load_lds16(bBase + (size_t)8 * K + k0, bLds + 512);
        __syncthreads();
        #pragma unroll
        for (int s = 0; s < 2; s++) {
            bf16x8 af[2], bfv[2];
            #pragma unroll
            for (int i = 0; i < 2; i++) {
                int row = wm + i * 16 + mrel;
                af[i] = ld_frag(&lds_a[row * 64 + (((s * 4 + kq) ^ (row & 7)) * 8)]);
            }
            #pragma unroll
            for (int j = 0; j < 2; j++) {
                int row = wn + j * 16 + mrel;
                bfv[j] = ld_frag(&lds_b[row * 64 + (((s * 4 + kq) ^ (row & 7)) * 8)]);
            }
            #pragma unroll
            for (int i = 0; i < 2; i++)
                #pragma unroll
                for (int j = 0; j < 2; j++)
                    acc[i][j] = __builtin_amdgcn_mfma_f32_16x16x32_bf16(af[i], bfv[j], acc[i][j], 0, 0, 0);
        }
        __syncthreads();
    }

    int quad = lane >> 4;
    #pragma unroll
    for (int j = 0; j < 2; j++) {
        int col = bn + wn + j * 16 + mrel;
        float bv = bias[col];
        #pragma unroll
        for (int i = 0; i < 2; i++) {
            #pragma unroll
            for (int reg = 0; reg < 4; reg++) {
                int row = bm + wm + i * 16 + quad * 4 + reg;
                C[(size_t)row * 1024 + col] = acc[i][j][reg] + bv;
            }
        }
    }
}

// ---------------- per-chunk KV state (MFMA) -> bf16, coalesced via LDS ----------------
__global__ __launch_bounds__(256) void chunk_kv_mfma(const ushort* __restrict__ kp,
                                                     const ushort* __restrict__ vp,
                                                     ushort* __restrict__ statesb) {
    __shared__ ushort Kt[64 * LT];
    __shared__ ushort Vt[64 * LT];
    int bx = blockIdx.x;
    int c = bx & 31, h = (bx >> 5) & 15, b = bx >> 9;
    int t = threadIdx.x, lane = t & 63, w = t >> 6;
    size_t rowbase = (size_t)(b * SEQ + c * 64);
    int r = t >> 2, cc = t & 3;
    const uint4* gk = (const uint4*)(kp + (rowbase + r) * D_MODEL + h * 64 + cc * 16);
    const uint4* gv = (const uint4*)(vp + (rowbase + r) * D_MODEL + h * 64 + cc * 16);
    uint4 k0 = gk[0], k1 = gk[1], v0 = gv[0], v1 = gv[1];
    {
        us16x8 ka = __builtin_bit_cast(us16x8, k0), kb = __builtin_bit_cast(us16x8, k1);
        us16x8 va = __builtin_bit_cast(us16x8, v0), vb = __builtin_bit_cast(us16x8, v1);
        #pragma unroll
        for (int i = 0; i < 8; i++) {
            Kt[(cc * 16 + i) * LT + r]     = ka[i];
            Kt[(cc * 16 + 8 + i) * LT + r] = kb[i];
            Vt[(cc * 16 + i) * LT + r]     = va[i];
            Vt[(cc * 16 + 8 + i) * LT + r] = vb[i];
        }
    }
    __syncthreads();
    int mrel = lane & 15, q8 = (lane >> 4) * 8, band = w * 16, quad = lane >> 4;
    bf16x8 af[2];
    af[0] = ld_frag(&Vt[(band + mrel) * LT + q8]);
    af[1] = ld_frag(&Vt[(band + mrel) * LT + 32 + q8]);
    f32x4 acc[4];
    #pragma unroll
    for (int dt = 0; dt < 4; dt++) acc[dt] = (f32x4){0.f, 0.f, 0.f, 0.f};
    #pragma unroll
    for (int dt = 0; dt < 4; dt++)
        #pragma unroll
        for (int kk = 0; kk < 2; kk++)
            acc[dt] = __builtin_amdgcn_mfma_f32_16x16x32_bf16(
                af[kk], ld_frag(&Kt[(dt * 16 + mrel) * LT + kk * 32 + q8]), acc[dt], 0, 0, 0);
    __syncthreads();   // all waves done reading Kt/Vt
    #pragma unroll
    for (int dt = 0; dt < 4; dt++)
        #pragma unroll
        for (int reg = 0; reg < 4; reg++)
            Kt[(band + quad * 4 + reg) * LT + dt * 16 + mrel] = f2bf(acc[dt][reg]);
    __syncthreads();
    {
        bf16x8 s0 = ld_frag(&Kt[r * LT + cc * 16]);
        bf16x8 s1 = ld_frag(&Kt[r * LT + cc * 16 + 8]);
        uint4* dst = (uint4*)(statesb + (size_t)bx * 4096 + r * 64 + cc * 16);
        dst[0] = __builtin_bit_cast(uint4, s0);
        dst[1] = __builtin_bit_cast(uint4, s1);
    }
}

// ---------------- exclusive prefix over chunks, bf16 in place ----------------
__global__ __launch_bounds__(256) void prefix_kernel(ushort* __restrict__ statesb) {
    int bh = blockIdx.y;
    int e = blockIdx.x * 256 + threadIdx.x;
    ushort* p = statesb + (size_t)bh * NCHUNK * 4096 + e;
    float run = 0.f;
    for (int cb = 0; cb < NCHUNK; cb += 8) {
        float vals[8];
        #pragma unroll
        for (int u = 0; u < 8; u++) vals[u] = bf2f(p[(size_t)(cb + u) * 4096]);
        #pragma unroll
        for (int u = 0; u < 8; u++) {
            p[(size_t)(cb + u) * 4096] = f2bf(run);
            run += vals[u];
        }
    }
}

// ---------------- per-chunk attention (MFMA): O = Q'·S^T + causal(Q'K^T)·V ----------------
__global__ __launch_bounds__(256) void attn_mfma(const ushort* __restrict__ qp,
                                                 const ushort* __restrict__ kp,
                                                 const ushort* __restrict__ vp,
                                                 const ushort* __restrict__ statesb,
                                                 ushort* __restrict__ attn_out) {
    __shared__ ushort Qs[64 * LT];
    __shared__ ushort Ks[64 * LT];
    __shared__ ushort Vt[64 * LT];
    __shared__ ushort St[64 * LT];
    __shared__ ushort Ps[64 * LT];
    int bx = blockIdx.x;
    int c = bx & 31, h = (bx >> 5) & 15, b = bx >> 9;
    int t = threadIdx.x, lane = t & 63, w = t >> 6;
    size_t rowbase = (size_t)(b * SEQ + c * 64);
    int r = t >> 2, cc = t & 3;
    {
        const uint4* gq = (const uint4*)(qp + (rowbase + r) * D_MODEL + h * 64 + cc * 16);
        const uint4* gk = (const uint4*)(kp + (rowbase + r) * D_MODEL + h * 64 + cc * 16);
        const uint4* gv = (const uint4*)(vp + (rowbase + r) * D_MODEL + h * 64 + cc * 16);
        const uint4* gs = (const uint4*)(statesb + (size_t)bx * 4096 + t * 16);
        uint4 q0 = gq[0], q1 = gq[1];
        uint4 k0 = gk[0], k1 = gk[1];
        uint4 v0 = gv[0], v1 = gv[1];
        uint4 s0 = gs[0], s1 = gs[1];
        st16(&Qs[r * LT + cc * 16], q0, q1);
        st16(&Ks[r * LT + cc * 16], k0, k1);
        st16(&St[r * LT + cc * 16], s0, s1);
        us16x8 va = __builtin_bit_cast(us16x8, v0), vb = __builtin_bit_cast(us16x8, v1);
        #pragma unroll
        for (int i = 0; i < 8; i++) {
            Vt[(cc * 16 + i) * LT + r]     = va[i];
            Vt[(cc * 16 + 8 + i) * LT + r] = vb[i];
        }
    }
    __syncthreads();

    int mrel = lane & 15, q8 = (lane >> 4) * 8, quad = lane >> 4, band = w * 16;
    bf16x8 af[2];
    af[0] = ld_frag(&Qs[(band + mrel) * LT + q8]);
    af[1] = ld_frag(&Qs[(band + mrel) * LT + 32 + q8]);

    f32x4 oacc[4];
    #pragma unroll
    for (int dt = 0; dt < 4; dt++) oacc[dt] = (f32x4){0.f, 0.f, 0.f, 0.f};
    #pragma unroll
    for (int dt = 0; dt < 4; dt++)
        #pragma unroll
        for (int kk = 0; kk < 2; kk++)
            oacc[dt] = __builtin_amdgcn_mfma_f32_16x16x32_bf16(
                af[kk], ld_frag(&St[(dt * 16 + mrel) * LT + kk * 32 + q8]), oacc[dt], 0, 0, 0);

    f32x4 pacc[4];
    #pragma unroll
    for (int jt = 0; jt < 4; jt++) pacc[jt] = (f32x4){0.f, 0.f, 0.f, 0.f};
    #pragma unroll
    for (int jt = 0; jt < 4; jt++) {
        if (jt <= w) {
            #pragma unroll
            for (int kk = 0; kk < 2; kk++)
                pacc[jt] = __builtin_amdgcn_mfma_f32_16x16x32_bf16(
                    af[kk], ld_frag(&Ks[(jt * 16 + mrel) * LT + kk * 32 + q8]), pacc[jt], 0, 0, 0);
        }
    }
    #pragma unroll
    for (int jt = 0; jt < 4; jt++) {
        #pragma unroll
        for (int reg = 0; reg < 4; reg++) {
            int i = band + quad * 4 + reg;
            int j = jt * 16 + mrel;
            float val = (jt <= w && j <= i) ? pacc[jt][reg] : 0.f;
            Ps[i * LT + j] = f2bf(val);
        }
    }
    __syncthreads();

    bf16x8 pf0 = ld_frag(&Ps[(band + mrel) * LT + q8]);
    #pragma unroll
    for (int dt = 0; dt < 4; dt++)
        oacc[dt] = __builtin_amdgcn_mfma_f32_16x16x32_bf16(
            pf0, ld_frag(&Vt[(dt * 16 + mrel) * LT + q8]), oacc[dt], 0, 0, 0);
    if (w >= 2) {
        bf16x8 pf1 = ld_frag(&Ps[(band + mrel) * LT + 32 + q8]);
        #pragma unroll
        for (int dt = 0; dt < 4; dt++)
            oacc[dt] = __builtin_amdgcn_mfma_f32_16x16x32_bf16(
                pf1, ld_frag(&Vt[(dt * 16 + mrel) * LT + 32 + q8]), oacc[dt], 0, 0, 0);
    }

    #pragma unroll
    for (int dt = 0; dt < 4; dt++) {
        #pragma unroll
        for (int reg = 0; reg < 4; reg++) {
            size_t row = rowbase + band + quad * 4 + reg;
            int col = h * 64 + dt * 16 + mrel;
            attn_out[row * D_MODEL + col] = f2bf(oacc[dt][reg]);
        }
    }
}

// ---------------- host launch ----------------
extern "C" void kernel_launch(void* const* d_in, const int* in_sizes, int n_in,
                              void* d_out, int out_size, void* d_ws, size_t ws_size,
                              hipStream_t stream) {
    (void)in_sizes; (void)n_in; (void)out_size; (void)ws_size;
    const float* x  = (const float*)d_in[0];
    const float* Wq = (const float*)d_in[1];
    const float* bq = (const float*)d_in[2];
    const float* Wk = (const float*)d_in[3];
    const float* bk = (const float*)d_in[4];
    const float* Wv = (const float*)d_in[5];
    const float* bv = (const float*)d_in[6];
    const float* Wo = (const float*)d_in[7];
    const float* bo = (const float*)d_in[8];
    const float* gamma = (const float*)d_in[9];
    float* out = (float*)d_out;

    uint8_t* w = (uint8_t*)d_ws;
    ushort* xb    = (ushort*)w; w += (size_t)XN * 2;            // 8 MB; reused as bf16 attn
    ushort* wqkvb = (ushort*)w; w += (size_t)3 * WN * 2;        // 6 MB
    ushort* wob   = (ushort*)w; w += (size_t)WN * 2;            // 2 MB
    ushort* qb  = (ushort*)w; w += (size_t)XN * 2;              // 8 MB
    ushort* kb  = (ushort*)w; w += (size_t)XN * 2;
    ushort* vb  = (ushort*)w; w += (size_t)XN * 2;
    ushort* statesb = (ushort*)w; w += (size_t)BATCH * NUM_HEADS * NCHUNK * 4096 * 2; // 8 MB
    float*  decay   = (float*)w;  w += (size_t)SEQ * NUM_HEADS * 4;

    cast_all_kernel<<<CAST_BLOCKS + (SEQ * NUM_HEADS) / 256, 256, 0, stream>>>(
        x, Wq, Wk, Wv, Wo, xb, gamma, decay);

    // fused QKV projection: 128x64 tiles -> 1536 blocks (6/CU), bf16 out, decay in q
    gemm_qkv<<<dim3(3072 / 64, M_TOT / 128), 256, 0, stream>>>(
        xb, wqkvb, bq, bk, bv, qb, kb, vb, decay);

    int nblk = BATCH * NUM_HEADS * NCHUNK;  // 1024
    chunk_kv_mfma<<<nblk, 256, 0, stream>>>(kb, vb, statesb);
    prefix_kernel<<<dim3(16, 32), 256, 0, stream>>>(statesb);
    attn_mfma<<<nblk, 256, 0, stream>>>(qb, kb, vb, statesb, xb);   // bf16 attn into xb

    // output projection: 64x64 tiles -> 1024 blocks (4/CU co-residency), fp32 out
    gemm64_wo<<<dim3(1024 / 64, M_TOT / 64), 256, 0, stream>>>(xb, wob, bo, out);
}